// Round 10
// baseline (95.535 us; speedup 1.0000x reference)
//
#include <hip/hip_runtime.h>
#include <hip/hip_fp16.h>
#include <math.h>

#define N_NODES 50000
#define N_EDGES 1600000
#define ET (N_EDGES + N_NODES)
#define F_OUT 64
#define F_IN 128
#define SLOPE 0.2f
#define BSHIFT 6                               // 64 nodes per bucket
#define BNODES 64
#define NBUCK ((N_NODES + BNODES - 1) >> BSHIFT)   // 782 buckets
#define CAP 2496                               // mean 2112 + 8.5 sigma
#define EPB 4096                               // edges per partition block
#define PBLOCKS ((ET + EPB - 1) / EPB)         // 403

typedef _Float16 half8 __attribute__((ext_vector_type(8)));
typedef _Float16 half4 __attribute__((ext_vector_type(4)));
typedef float f32x4 __attribute__((ext_vector_type(4)));

// ---------------- MFMA GEMM: xp(f16) = x @ W + attention logits (+bcur zero) ----------------
__global__ __launch_bounds__(256) void gemm_kernel(const float4* __restrict__ x4,
                                                   const float* __restrict__ W,
                                                   const float* __restrict__ a_src,
                                                   const float* __restrict__ a_dst,
                                                   _Float16* __restrict__ xph,
                                                   float* __restrict__ alpha_s,
                                                   float* __restrict__ alpha_d,
                                                   int* __restrict__ bcur) {
    __shared__ _Float16 xs[64][136];          // padded: row stride 272B
    int t = threadIdx.x;
    if (blockIdx.x == 0)
        for (int i = t; i < NBUCK; i += 256) bcur[i] = 0;
    int wave = t >> 6, lane = t & 63;
    int g = lane >> 4, c16 = lane & 15;

    // stage x rows -> fp16 LDS
    size_t rbase = (size_t)blockIdx.x * 64;
#pragma unroll
    for (int i = 0; i < 8; ++i) {
        int idx = t + i * 256;                 // over 64*32 float4
        int row = idx >> 5, c4 = idx & 31;
        size_t gr = rbase + row;
        if (gr >= N_NODES) gr = N_NODES - 1;
        float4 v = x4[gr * (F_IN / 4) + c4];
        half4 hv = { (_Float16)v.x, (_Float16)v.y, (_Float16)v.z, (_Float16)v.w };
        *(half4*)&xs[row][c4 * 4] = hv;
    }

    // B fragments straight from global W (L2-resident 32 KB)
    half8 bw[4][4];
#pragma unroll
    for (int nt = 0; nt < 4; ++nt)
#pragma unroll
        for (int kt = 0; kt < 4; ++kt) {
            int col = nt * 16 + c16;
            int k0 = kt * 32 + g * 8;
#pragma unroll
            for (int e = 0; e < 8; ++e)
                bw[nt][kt][e] = (_Float16)W[(k0 + e) * F_OUT + col];
        }
    __syncthreads();

    int r0 = wave * 16;
    half8 af[4];
#pragma unroll
    for (int kt = 0; kt < 4; ++kt)
        af[kt] = *(const half8*)&xs[r0 + c16][kt * 32 + g * 8];

    f32x4 acc[4];
#pragma unroll
    for (int nt = 0; nt < 4; ++nt) {
        acc[nt] = (f32x4){0.f, 0.f, 0.f, 0.f};
#pragma unroll
        for (int kt = 0; kt < 4; ++kt)
            acc[nt] = __builtin_amdgcn_mfma_f32_16x16x32_f16(af[kt], bw[nt][kt], acc[nt], 0, 0, 0);
    }

    // epilogue: D layout row=g*4+r, col=nt*16+c16
    int growbase = (int)rbase + r0 + g * 4;
#pragma unroll
    for (int nt = 0; nt < 4; ++nt) {
#pragma unroll
        for (int r = 0; r < 4; ++r) {
            int row = growbase + r;
            if (row < N_NODES)
                xph[(size_t)row * F_OUT + nt * 16 + c16] = (_Float16)acc[nt][r];
        }
    }
    float asl[4], adl[4];
#pragma unroll
    for (int nt = 0; nt < 4; ++nt) {
        asl[nt] = a_src[nt * 16 + c16];
        adl[nt] = a_dst[nt * 16 + c16];
    }
#pragma unroll
    for (int r = 0; r < 4; ++r) {
        float ps = 0.f, pd = 0.f;
#pragma unroll
        for (int nt = 0; nt < 4; ++nt) {
            ps = fmaf(acc[nt][r], asl[nt], ps);
            pd = fmaf(acc[nt][r], adl[nt], pd);
        }
#pragma unroll
        for (int off = 1; off < 16; off <<= 1) {
            ps += __shfl_xor(ps, off);
            pd += __shfl_xor(pd, off);
        }
        int row = growbase + r;
        if (c16 == 0 && row < N_NODES) { alpha_s[row] = ps; alpha_d[row] = pd; }
    }
}

// ---------------- partition: single-pass rank capture, 16 edges/thread ----------------
__global__ __launch_bounds__(256) void part_kernel(const int* __restrict__ ei,
                                                   int* __restrict__ bcur,
                                                   unsigned* __restrict__ rec) {
    __shared__ int lc[NBUCK];
    __shared__ int lbase[NBUCK];
    int t = threadIdx.x;
    for (int b = t; b < NBUCK; b += 256) lc[b] = 0;
    __syncthreads();
    int e0 = blockIdx.x * EPB;

    unsigned u[16]; short bk[16]; unsigned short rk[16];
#pragma unroll
    for (int k = 0; k < 4; ++k) {
        int e = e0 + k * 1024 + t * 4;
        int4 sv, dv;
        if (e + 3 < N_EDGES) {                 // fast path: 16B aligned vector loads
            sv = *(const int4*)&ei[e];
            dv = *(const int4*)&ei[N_EDGES + e];
        } else {
            int* sp = (int*)&sv; int* dp = (int*)&dv;
#pragma unroll
            for (int j = 0; j < 4; ++j) {
                int ee = e + j;
                if (ee < N_EDGES)      { sp[j] = ei[ee]; dp[j] = ei[N_EDGES + ee]; }
                else if (ee < ET)      { sp[j] = dp[j] = ee - N_EDGES; }
                else                   { sp[j] = dp[j] = -1; }
            }
        }
        const int* sp = (const int*)&sv; const int* dp = (const int*)&dv;
#pragma unroll
        for (int j = 0; j < 4; ++j) {
            int i = k * 4 + j;
            int d = dp[j];
            if (d >= 0) {
                int b = d >> BSHIFT;
                bk[i] = (short)b;
                rk[i] = (unsigned short)atomicAdd(&lc[b], 1);
                u[i] = (unsigned)sp[j] | ((unsigned)d << 16);
            } else bk[i] = -1;
        }
    }
    __syncthreads();
    for (int b = t; b < NBUCK; b += 256)
        lbase[b] = lc[b] ? (b * CAP + atomicAdd(&bcur[b], lc[b])) : 0;
    __syncthreads();
#pragma unroll
    for (int i = 0; i < 16; ++i)
        if (bk[i] >= 0) rec[lbase[bk[i]] + rk[i]] = u[i];
}

// ---------------- fused bucket kernel: LDS CSR build + weights + gather ----------------
__device__ __forceinline__ void consume(unsigned u, uint2 h, bool valid,
                                        float4& acc, float& ws) {
    float w = __half2float(__ushort_as_half((unsigned short)(u >> 16)));
    w = valid ? w : 0.f;
    float2 f0 = __half22float2(__builtin_bit_cast(__half2, h.x));
    float2 f1 = __half22float2(__builtin_bit_cast(__half2, h.y));
    acc.x = fmaf(w, f0.x, acc.x);
    acc.y = fmaf(w, f0.y, acc.y);
    acc.z = fmaf(w, f1.x, acc.z);
    acc.w = fmaf(w, f1.y, acc.w);
    ws += w;
}

__global__ __launch_bounds__(256) void bucket_kernel(const unsigned* __restrict__ rec,
                                                     const int* __restrict__ bcur,
                                                     const float* __restrict__ as,
                                                     const float* __restrict__ ad,
                                                     const __half* __restrict__ xp,
                                                     const float* __restrict__ bias,
                                                     float* __restrict__ out) {
    __shared__ unsigned lrec[CAP];            // 10 KB
    __shared__ unsigned lcsr[CAP];            // 10 KB
    __shared__ int lcnt[BNODES], loff[BNODES], lcur[BNODES];
    __shared__ float adl[BNODES];
    int t = threadIdx.x;
    int b = blockIdx.x;
    int n0 = b << BSHIFT;
    int r0 = b * CAP;
    int cnt_b = bcur[b];
    if (t < BNODES) {
        lcnt[t] = 0; lcur[t] = 0;
        adl[t] = (n0 + t < N_NODES) ? ad[n0 + t] : 0.f;
    }
    __syncthreads();
    // stage records + per-node histogram
    for (int i = t; i < cnt_b; i += 256) {
        unsigned u = rec[r0 + i];
        lrec[i] = u;
        atomicAdd(&lcnt[(u >> 16) & (BNODES - 1)], 1);
    }
    __syncthreads();
    // exclusive scan of 64 counters in wave 0
    if (t < BNODES) {
        int v = lcnt[t];
        int incl = v;
#pragma unroll
        for (int off = 1; off < BNODES; off <<= 1) {
            int n = __shfl_up(incl, off);
            if (t >= off) incl += n;
        }
        loff[t] = incl - v;
    }
    __syncthreads();
    // permute into CSR order + compute edge weight
    for (int i = t; i < cnt_b; i += 256) {
        unsigned u = lrec[i];
        int dl = (u >> 16) & (BNODES - 1);
        int s = u & 0xFFFFu;
        float ev = as[s] + adl[dl];
        ev = ev > 0.f ? ev : SLOPE * ev;
        float w = __expf(ev);
        int pos = atomicAdd(&lcur[dl], 1);
        lcsr[loff[dl] + pos] =
            (unsigned)s | ((unsigned)__half_as_ushort(__float2half(w)) << 16);
    }
    __syncthreads();
    // gather: wave per node (16 nodes/wave), 4 edge-streams, depth-4 pipeline
    int wave = t >> 6, lane = t & 63;
    int q = lane >> 4, f = lane & 15;
    const uint2* xp2 = (const uint2*)xp;
    for (int j = 0; j < 16; ++j) {
        int dl = wave * 16 + j;
        if (n0 + dl >= N_NODES) break;
        int start = loff[dl], cnt = lcnt[dl];
        int m = (cnt - q + 3) >> 2;            // stream-q edge count (may be <=0)
        int cm1 = start + cnt - 1;
        int p0 = start + q;
        unsigned u0 = lcsr[min(p0, cm1)];
        unsigned u1 = lcsr[min(p0 + 4, cm1)];
        unsigned u2 = lcsr[min(p0 + 8, cm1)];
        unsigned u3 = lcsr[min(p0 + 12, cm1)];
        uint2 h0 = xp2[(u0 & 0xFFFFu) * 16 + f];
        uint2 h1 = xp2[(u1 & 0xFFFFu) * 16 + f];
        uint2 h2 = xp2[(u2 & 0xFFFFu) * 16 + f];
        uint2 h3 = xp2[(u3 & 0xFFFFu) * 16 + f];
        float4 acc = make_float4(0.f, 0.f, 0.f, 0.f);
        float ws = 0.f;
        for (int i = 0; i < m; i += 4) {
            consume(u0, h0, true, acc, ws);
            if (i + 4 < m) { u0 = lcsr[p0 + (i + 4) * 4];
                             h0 = xp2[(u0 & 0xFFFFu) * 16 + f]; }
            consume(u1, h1, i + 1 < m, acc, ws);
            if (i + 5 < m) { u1 = lcsr[p0 + (i + 5) * 4];
                             h1 = xp2[(u1 & 0xFFFFu) * 16 + f]; }
            consume(u2, h2, i + 2 < m, acc, ws);
            if (i + 6 < m) { u2 = lcsr[p0 + (i + 6) * 4];
                             h2 = xp2[(u2 & 0xFFFFu) * 16 + f]; }
            consume(u3, h3, i + 3 < m, acc, ws);
            if (i + 7 < m) { u3 = lcsr[p0 + (i + 7) * 4];
                             h3 = xp2[(u3 & 0xFFFFu) * 16 + f]; }
        }
#pragma unroll
        for (int off = 16; off < 64; off <<= 1) {
            acc.x += __shfl_xor(acc.x, off);
            acc.y += __shfl_xor(acc.y, off);
            acc.z += __shfl_xor(acc.z, off);
            acc.w += __shfl_xor(acc.w, off);
            ws    += __shfl_xor(ws, off);
        }
        if (q == 0) {
            float inv = 1.f / ws;
            float4 bl = ((const float4*)bias)[f];
            float4 o;
            o.x = fmaf(acc.x, inv, bl.x);
            o.y = fmaf(acc.y, inv, bl.y);
            o.z = fmaf(acc.z, inv, bl.z);
            o.w = fmaf(acc.w, inv, bl.w);
            o.x = o.x > 0.f ? o.x : 0.f;
            o.y = o.y > 0.f ? o.y : 0.f;
            o.z = o.z > 0.f ? o.z : 0.f;
            o.w = o.w > 0.f ? o.w : 0.f;
            ((float4*)out)[(size_t)(n0 + dl) * 16 + f] = o;
        }
    }
}

extern "C" void kernel_launch(void* const* d_in, const int* in_sizes, int n_in,
                              void* d_out, int out_size, void* d_ws, size_t ws_size,
                              hipStream_t stream) {
    const float* x     = (const float*)d_in[0];
    const float* W     = (const float*)d_in[1];
    const float* a_src = (const float*)d_in[2];
    const float* a_dst = (const float*)d_in[3];
    const float* bias  = (const float*)d_in[4];
    const int*   ei    = (const int*)d_in[5];
    float* out = (float*)d_out;

    _Float16* xph   = (_Float16*)d_ws;                        // N*64 fp16
    float*  as      = (float*)(xph + (size_t)N_NODES * F_OUT);
    float*  ad      = as + N_NODES;
    int*    bcur    = (int*)(ad + N_NODES);                   // NBUCK
    unsigned* rec   = (unsigned*)(bcur + NBUCK + 64);         // NBUCK*CAP u32

    gemm_kernel<<<(N_NODES + 63) / 64, 256, 0, stream>>>(
        (const float4*)x, W, a_src, a_dst, xph, as, ad, bcur);
    part_kernel<<<PBLOCKS, 256, 0, stream>>>(ei, bcur, rec);
    bucket_kernel<<<NBUCK, 256, 0, stream>>>(rec, bcur, as, ad,
                                             (const __half*)xph, bias, out);
}

// Round 11
// 89.828 us; speedup vs baseline: 1.0635x; 1.0635x over previous
//
#include <hip/hip_runtime.h>
#include <hip/hip_fp16.h>
#include <math.h>

#define N_NODES 50000
#define N_EDGES 1600000
#define ET (N_EDGES + N_NODES)
#define F_OUT 64
#define F_IN 128
#define SLOPE 0.2f
#define BSHIFT 7                               // 128 nodes per bucket
#define BNODES 128
#define NBUCK ((N_NODES + BNODES - 1) >> BSHIFT)   // 391 buckets
#define CAP 4736                               // mean 4224 + 8 sigma
#define EPB 4096                               // edges per partition block
#define PBLOCKS ((ET + EPB - 1) / EPB)         // 403
#define GEMM_BLOCKS ((N_NODES + 63) / 64)      // 782

typedef _Float16 half8 __attribute__((ext_vector_type(8)));
typedef _Float16 half4 __attribute__((ext_vector_type(4)));
typedef float f32x4 __attribute__((ext_vector_type(4)));

// ---------------- fused front kernel: blocks [0,PBLOCKS) = partition, rest = GEMM ----------------
__global__ __launch_bounds__(256) void gp_kernel(const float4* __restrict__ x4,
                                                 const float* __restrict__ W,
                                                 const float* __restrict__ a_src,
                                                 const float* __restrict__ a_dst,
                                                 const int* __restrict__ ei,
                                                 _Float16* __restrict__ xph,
                                                 float* __restrict__ alpha_s,
                                                 float* __restrict__ alpha_d,
                                                 int* __restrict__ bcur,
                                                 unsigned* __restrict__ rec) {
    __shared__ _Float16 xs[64][136];          // 17.4 KB (gemm path)
    __shared__ int lc[NBUCK];                 // 1.6 KB (part path)
    __shared__ int lbase[NBUCK];              // 1.6 KB (part path)
    int t = threadIdx.x;

    if (blockIdx.x < PBLOCKS) {
        // ================= partition: single-pass rank capture, 16 edges/thread =================
        for (int b = t; b < NBUCK; b += 256) lc[b] = 0;
        __syncthreads();
        int e0 = blockIdx.x * EPB;

        unsigned u[16]; short bk[16]; unsigned short rk[16];
#pragma unroll
        for (int k = 0; k < 4; ++k) {
            int e = e0 + k * 1024 + t * 4;
            int4 sv, dv;
            if (e + 3 < N_EDGES) {             // fast path: 16B aligned vector loads
                sv = *(const int4*)&ei[e];
                dv = *(const int4*)&ei[N_EDGES + e];
            } else {
                int* sp = (int*)&sv; int* dp = (int*)&dv;
#pragma unroll
                for (int j = 0; j < 4; ++j) {
                    int ee = e + j;
                    if (ee < N_EDGES)      { sp[j] = ei[ee]; dp[j] = ei[N_EDGES + ee]; }
                    else if (ee < ET)      { sp[j] = dp[j] = ee - N_EDGES; }
                    else                   { sp[j] = dp[j] = -1; }
                }
            }
            const int* sp = (const int*)&sv; const int* dp = (const int*)&dv;
#pragma unroll
            for (int j = 0; j < 4; ++j) {
                int i = k * 4 + j;
                int d = dp[j];
                if (d >= 0) {
                    int b = d >> BSHIFT;
                    bk[i] = (short)b;
                    rk[i] = (unsigned short)atomicAdd(&lc[b], 1);
                    u[i] = (unsigned)sp[j] | ((unsigned)d << 16);
                } else bk[i] = -1;
            }
        }
        __syncthreads();
        for (int b = t; b < NBUCK; b += 256)
            lbase[b] = lc[b] ? (b * CAP + atomicAdd(&bcur[b], lc[b])) : 0;
        __syncthreads();
#pragma unroll
        for (int i = 0; i < 16; ++i)
            if (bk[i] >= 0) rec[lbase[bk[i]] + rk[i]] = u[i];
        return;
    }

    // ================= MFMA GEMM: xp(f16) = x @ W + attention logits =================
    int wave = t >> 6, lane = t & 63;
    int g = lane >> 4, c16 = lane & 15;

    size_t rbase = (size_t)(blockIdx.x - PBLOCKS) * 64;
#pragma unroll
    for (int i = 0; i < 8; ++i) {
        int idx = t + i * 256;                 // over 64*32 float4
        int row = idx >> 5, c4 = idx & 31;
        size_t gr = rbase + row;
        if (gr >= N_NODES) gr = N_NODES - 1;
        float4 v = x4[gr * (F_IN / 4) + c4];
        half4 hv = { (_Float16)v.x, (_Float16)v.y, (_Float16)v.z, (_Float16)v.w };
        *(half4*)&xs[row][c4 * 4] = hv;
    }

    // B fragments straight from global W (L2-resident 32 KB)
    half8 bw[4][4];
#pragma unroll
    for (int nt = 0; nt < 4; ++nt)
#pragma unroll
        for (int kt = 0; kt < 4; ++kt) {
            int col = nt * 16 + c16;
            int k0 = kt * 32 + g * 8;
#pragma unroll
            for (int e = 0; e < 8; ++e)
                bw[nt][kt][e] = (_Float16)W[(k0 + e) * F_OUT + col];
        }
    __syncthreads();

    int r0 = wave * 16;
    half8 af[4];
#pragma unroll
    for (int kt = 0; kt < 4; ++kt)
        af[kt] = *(const half8*)&xs[r0 + c16][kt * 32 + g * 8];

    f32x4 acc[4];
#pragma unroll
    for (int nt = 0; nt < 4; ++nt) {
        acc[nt] = (f32x4){0.f, 0.f, 0.f, 0.f};
#pragma unroll
        for (int kt = 0; kt < 4; ++kt)
            acc[nt] = __builtin_amdgcn_mfma_f32_16x16x32_f16(af[kt], bw[nt][kt], acc[nt], 0, 0, 0);
    }

    // epilogue: D layout row=g*4+r, col=nt*16+c16
    int growbase = (int)rbase + r0 + g * 4;
#pragma unroll
    for (int nt = 0; nt < 4; ++nt) {
#pragma unroll
        for (int r = 0; r < 4; ++r) {
            int row = growbase + r;
            if (row < N_NODES)
                xph[(size_t)row * F_OUT + nt * 16 + c16] = (_Float16)acc[nt][r];
        }
    }
    float asl[4], adl[4];
#pragma unroll
    for (int nt = 0; nt < 4; ++nt) {
        asl[nt] = a_src[nt * 16 + c16];
        adl[nt] = a_dst[nt * 16 + c16];
    }
#pragma unroll
    for (int r = 0; r < 4; ++r) {
        float ps = 0.f, pd = 0.f;
#pragma unroll
        for (int nt = 0; nt < 4; ++nt) {
            ps = fmaf(acc[nt][r], asl[nt], ps);
            pd = fmaf(acc[nt][r], adl[nt], pd);
        }
#pragma unroll
        for (int off = 1; off < 16; off <<= 1) {
            ps += __shfl_xor(ps, off);
            pd += __shfl_xor(pd, off);
        }
        int row = growbase + r;
        if (c16 == 0 && row < N_NODES) { alpha_s[row] = ps; alpha_d[row] = pd; }
    }
}

// ---------------- scan helper (8 waves) ----------------
__device__ __forceinline__ int block_incl_scan(int v, int t, int* wsum) {
    int lane = t & 63, wave = t >> 6;
#pragma unroll
    for (int off = 1; off < 64; off <<= 1) {
        int n = __shfl_up(v, off);
        if (lane >= off) v += n;
    }
    if (lane == 63) wsum[wave] = v;
    __syncthreads();
    int add = 0;
    for (int w = 0; w < wave; ++w) add += wsum[w];
    return v + add;
}

// ---------------- per-bucket CSR build + edge-weight precompute ----------------
__global__ __launch_bounds__(512) void csrb_kernel(const unsigned* __restrict__ rec,
                                                   const int* __restrict__ bcur,
                                                   const float* __restrict__ as,
                                                   const float* __restrict__ ad,
                                                   int* __restrict__ offsets,
                                                   int* __restrict__ counts,
                                                   unsigned* __restrict__ wcsr) {
    __shared__ unsigned lrec[CAP];            // 18.9 KB
    __shared__ int lcnt[BNODES], loff[BNODES], lcur[BNODES];
    __shared__ float adl[BNODES];
    __shared__ int wsum[8];
    int t = threadIdx.x;
    int b = blockIdx.x;
    int n0 = b << BSHIFT;
    int r0 = b * CAP;
    int cnt_b = bcur[b];
    if (t < BNODES) {
        lcnt[t] = 0; lcur[t] = 0;
        adl[t] = (n0 + t < N_NODES) ? ad[n0 + t] : 0.f;
    }
    for (int i = t; i < cnt_b; i += 512) lrec[i] = rec[r0 + i];
    __syncthreads();
    for (int i = t; i < cnt_b; i += 512)
        atomicAdd(&lcnt[(lrec[i] >> 16) & (BNODES - 1)], 1);
    __syncthreads();
    int v = (t < BNODES) ? lcnt[t] : 0;
    int incl = block_incl_scan(v, t, wsum);
    if (t < BNODES) {
        loff[t] = incl - v;
        if (n0 + t < N_NODES) { counts[n0 + t] = v; offsets[n0 + t] = r0 + incl - v; }
    }
    __syncthreads();
    for (int i = t; i < cnt_b; i += 512) {
        unsigned u = lrec[i];
        int dl = (u >> 16) & (BNODES - 1);
        int s = u & 0xFFFFu;
        float ev = as[s] + adl[dl];
        ev = ev > 0.f ? ev : SLOPE * ev;
        float w = __expf(ev);
        int pos = atomicAdd(&lcur[dl], 1);
        wcsr[r0 + loff[dl] + pos] =
            (unsigned)s | ((unsigned)__half_as_ushort(__float2half(w)) << 16);
    }
}

// ---------------- gather: wave/dst, 4 edge-streams, depth-4 software pipeline ----------------
#define CONSUME(u_, h_)                                                        \
    {                                                                          \
        float w = __half2float(__ushort_as_half((unsigned short)((u_) >> 16)));\
        float2 f0 = __half22float2(__builtin_bit_cast(__half2, (h_).x));       \
        float2 f1 = __half22float2(__builtin_bit_cast(__half2, (h_).y));       \
        acc.x = fmaf(w, f0.x, acc.x);                                          \
        acc.y = fmaf(w, f0.y, acc.y);                                          \
        acc.z = fmaf(w, f1.x, acc.z);                                          \
        acc.w = fmaf(w, f1.y, acc.w);                                          \
        ws += w;                                                               \
    }

__global__ __launch_bounds__(256) void gather_kernel(const unsigned* __restrict__ wcsr,
                                                     const int* __restrict__ offsets,
                                                     const int* __restrict__ counts,
                                                     const __half* __restrict__ xp,
                                                     const float* __restrict__ bias,
                                                     float* __restrict__ out) {
    __shared__ unsigned stage[4][64];
    int wave = threadIdx.x >> 6, lane = threadIdx.x & 63;
    int d = blockIdx.x * 4 + wave;
    if (d >= N_NODES) return;
    int start = offsets[d], cnt = counts[d];
    int q = lane >> 4, f = lane & 15;
    const uint2* xp2 = (const uint2*)xp;
    float4 acc = make_float4(0.f, 0.f, 0.f, 0.f);
    float ws = 0.f;

    for (int jb = 0; jb < cnt; jb += 64) {
        int iters = min(cnt - jb, 64);
        unsigned rc = (lane < iters) ? wcsr[start + jb + lane] : 0u;
        stage[wave][lane] = rc;               // wave-private; lanes >= iters write 0
        int m = (iters - q + 3) >> 2;         // this quarter's edge count
        int M4 = (m + 3) & ~3;                // rounded up; extras have u=0 -> w=0
        unsigned u0 = stage[wave][q];
        unsigned u1 = stage[wave][q + 4];
        unsigned u2 = stage[wave][q + 8];
        unsigned u3 = stage[wave][q + 12];
        uint2 h0 = xp2[(u0 & 0xFFFFu) * 16 + f];
        uint2 h1 = xp2[(u1 & 0xFFFFu) * 16 + f];
        uint2 h2 = xp2[(u2 & 0xFFFFu) * 16 + f];
        uint2 h3 = xp2[(u3 & 0xFFFFu) * 16 + f];
        for (int i = 0; i < M4; i += 4) {
            CONSUME(u0, h0);
            if (i + 4 < M4) { u0 = stage[wave][q + (i + 4) * 4];
                              h0 = xp2[(u0 & 0xFFFFu) * 16 + f]; }
            CONSUME(u1, h1);
            if (i + 5 < M4) { u1 = stage[wave][q + (i + 5) * 4];
                              h1 = xp2[(u1 & 0xFFFFu) * 16 + f]; }
            CONSUME(u2, h2);
            if (i + 6 < M4) { u2 = stage[wave][q + (i + 6) * 4];
                              h2 = xp2[(u2 & 0xFFFFu) * 16 + f]; }
            CONSUME(u3, h3);
            if (i + 7 < M4) { u3 = stage[wave][q + (i + 7) * 4];
                              h3 = xp2[(u3 & 0xFFFFu) * 16 + f]; }
        }
    }
#pragma unroll
    for (int off = 16; off < 64; off <<= 1) {
        acc.x += __shfl_xor(acc.x, off);
        acc.y += __shfl_xor(acc.y, off);
        acc.z += __shfl_xor(acc.z, off);
        acc.w += __shfl_xor(acc.w, off);
        ws    += __shfl_xor(ws, off);
    }
    if (q == 0) {
        float inv = 1.f / ws;
        float4 bl = ((const float4*)bias)[f];
        float4 o;
        o.x = fmaf(acc.x, inv, bl.x);
        o.y = fmaf(acc.y, inv, bl.y);
        o.z = fmaf(acc.z, inv, bl.z);
        o.w = fmaf(acc.w, inv, bl.w);
        o.x = o.x > 0.f ? o.x : 0.f;
        o.y = o.y > 0.f ? o.y : 0.f;
        o.z = o.z > 0.f ? o.z : 0.f;
        o.w = o.w > 0.f ? o.w : 0.f;
        ((float4*)out)[(size_t)d * 16 + f] = o;
    }
}

extern "C" void kernel_launch(void* const* d_in, const int* in_sizes, int n_in,
                              void* d_out, int out_size, void* d_ws, size_t ws_size,
                              hipStream_t stream) {
    const float* x     = (const float*)d_in[0];
    const float* W     = (const float*)d_in[1];
    const float* a_src = (const float*)d_in[2];
    const float* a_dst = (const float*)d_in[3];
    const float* bias  = (const float*)d_in[4];
    const int*   ei    = (const int*)d_in[5];
    float* out = (float*)d_out;

    _Float16* xph   = (_Float16*)d_ws;                        // N*64 fp16
    float*  as      = (float*)(xph + (size_t)N_NODES * F_OUT);
    float*  ad      = as + N_NODES;
    int*    counts  = (int*)(ad + N_NODES);                   // N
    int*    offsets = counts + N_NODES;                       // N
    int*    bcur    = offsets + N_NODES;                      // NBUCK
    unsigned* rec   = (unsigned*)(bcur + NBUCK + 64);         // NBUCK*CAP u32
    unsigned* wcsr  = rec + (size_t)NBUCK * CAP;              // NBUCK*CAP u32

    hipMemsetAsync(bcur, 0, NBUCK * sizeof(int), stream);
    gp_kernel<<<PBLOCKS + GEMM_BLOCKS, 256, 0, stream>>>(
        (const float4*)x, W, a_src, a_dst, ei, xph, as, ad, bcur, rec);
    csrb_kernel<<<NBUCK, 512, 0, stream>>>(rec, bcur, as, ad, offsets, counts, wcsr);
    gather_kernel<<<(N_NODES + 3) / 4, 256, 0, stream>>>(wcsr, offsets, counts,
                                                         (const __half*)xph, bias, out);
}

// Round 12
// 87.145 us; speedup vs baseline: 1.0963x; 1.0308x over previous
//
#include <hip/hip_runtime.h>
#include <hip/hip_fp16.h>
#include <math.h>

#define N_NODES 50000
#define N_EDGES 1600000
#define ET (N_EDGES + N_NODES)
#define F_OUT 64
#define F_IN 128
#define SLOPE 0.2f
#define BSHIFT 7                               // 128 nodes per bucket
#define BNODES 128
#define NBUCK ((N_NODES + BNODES - 1) >> BSHIFT)   // 391 buckets
#define CAP 4736                               // mean 4224 + 8 sigma
#define EPB 4096                               // edges per partition block
#define PBLOCKS ((ET + EPB - 1) / EPB)         // 403

typedef _Float16 half8 __attribute__((ext_vector_type(8)));
typedef _Float16 half4 __attribute__((ext_vector_type(4)));
typedef float f32x4 __attribute__((ext_vector_type(4)));

// ---------------- MFMA GEMM: xp(f16) = x @ W + attention logits (+bcur zero) ----------------
__global__ __launch_bounds__(256) void gemm_kernel(const float4* __restrict__ x4,
                                                   const float* __restrict__ W,
                                                   const float* __restrict__ a_src,
                                                   const float* __restrict__ a_dst,
                                                   _Float16* __restrict__ xph,
                                                   float* __restrict__ alpha_s,
                                                   float* __restrict__ alpha_d,
                                                   int* __restrict__ bcur) {
    __shared__ _Float16 xs[64][136];          // padded: row stride 272B
    int t = threadIdx.x;
    if (blockIdx.x == 0)
        for (int i = t; i < NBUCK; i += 256) bcur[i] = 0;
    int wave = t >> 6, lane = t & 63;
    int g = lane >> 4, c16 = lane & 15;

    size_t rbase = (size_t)blockIdx.x * 64;
#pragma unroll
    for (int i = 0; i < 8; ++i) {
        int idx = t + i * 256;                 // over 64*32 float4
        int row = idx >> 5, c4 = idx & 31;
        size_t gr = rbase + row;
        if (gr >= N_NODES) gr = N_NODES - 1;
        float4 v = x4[gr * (F_IN / 4) + c4];
        half4 hv = { (_Float16)v.x, (_Float16)v.y, (_Float16)v.z, (_Float16)v.w };
        *(half4*)&xs[row][c4 * 4] = hv;
    }

    // B fragments straight from global W (L2-resident 32 KB)
    half8 bw[4][4];
#pragma unroll
    for (int nt = 0; nt < 4; ++nt)
#pragma unroll
        for (int kt = 0; kt < 4; ++kt) {
            int col = nt * 16 + c16;
            int k0 = kt * 32 + g * 8;
#pragma unroll
            for (int e = 0; e < 8; ++e)
                bw[nt][kt][e] = (_Float16)W[(k0 + e) * F_OUT + col];
        }
    __syncthreads();

    int r0 = wave * 16;
    half8 af[4];
#pragma unroll
    for (int kt = 0; kt < 4; ++kt)
        af[kt] = *(const half8*)&xs[r0 + c16][kt * 32 + g * 8];

    f32x4 acc[4];
#pragma unroll
    for (int nt = 0; nt < 4; ++nt) {
        acc[nt] = (f32x4){0.f, 0.f, 0.f, 0.f};
#pragma unroll
        for (int kt = 0; kt < 4; ++kt)
            acc[nt] = __builtin_amdgcn_mfma_f32_16x16x32_f16(af[kt], bw[nt][kt], acc[nt], 0, 0, 0);
    }

    int growbase = (int)rbase + r0 + g * 4;
#pragma unroll
    for (int nt = 0; nt < 4; ++nt) {
#pragma unroll
        for (int r = 0; r < 4; ++r) {
            int row = growbase + r;
            if (row < N_NODES)
                xph[(size_t)row * F_OUT + nt * 16 + c16] = (_Float16)acc[nt][r];
        }
    }
    float asl[4], adl[4];
#pragma unroll
    for (int nt = 0; nt < 4; ++nt) {
        asl[nt] = a_src[nt * 16 + c16];
        adl[nt] = a_dst[nt * 16 + c16];
    }
#pragma unroll
    for (int r = 0; r < 4; ++r) {
        float ps = 0.f, pd = 0.f;
#pragma unroll
        for (int nt = 0; nt < 4; ++nt) {
            ps = fmaf(acc[nt][r], asl[nt], ps);
            pd = fmaf(acc[nt][r], adl[nt], pd);
        }
#pragma unroll
        for (int off = 1; off < 16; off <<= 1) {
            ps += __shfl_xor(ps, off);
            pd += __shfl_xor(pd, off);
        }
        int row = growbase + r;
        if (c16 == 0 && row < N_NODES) { alpha_s[row] = ps; alpha_d[row] = pd; }
    }
}

// ---------------- scan helper (4 waves, 256 threads) ----------------
__device__ __forceinline__ int block_incl_scan(int v, int t, int* wsum) {
    int lane = t & 63, wave = t >> 6;
#pragma unroll
    for (int off = 1; off < 64; off <<= 1) {
        int n = __shfl_up(v, off);
        if (lane >= off) v += n;
    }
    if (lane == 63) wsum[wave] = v;
    __syncthreads();
    int add = 0;
    for (int w = 0; w < wave; ++w) add += wsum[w];
    return v + add;
}

// ---------------- partition: rank capture + LDS-ordered coalesced write-out ----------------
__global__ __launch_bounds__(256) void part_kernel(const int* __restrict__ ei,
                                                   int* __restrict__ bcur,
                                                   unsigned* __restrict__ rec) {
    __shared__ int lc[NBUCK];                 // per-bucket count
    __shared__ int lbl[NBUCK];                // local exclusive base
    __shared__ int shift[NBUCK];              // global base - local base
    __shared__ unsigned lrec[EPB];            // 16 KB bucket-ordered image
    __shared__ int wsum[4];
    __shared__ int tot1;
    int t = threadIdx.x;
    for (int b = t; b < NBUCK; b += 256) lc[b] = 0;
    __syncthreads();
    int e0 = blockIdx.x * EPB;

    unsigned u[16]; short bk[16]; unsigned short rk[16];
#pragma unroll
    for (int k = 0; k < 4; ++k) {
        int e = e0 + k * 1024 + t * 4;
        int4 sv, dv;
        if (e + 3 < N_EDGES) {                 // fast path: 16B aligned vector loads
            sv = *(const int4*)&ei[e];
            dv = *(const int4*)&ei[N_EDGES + e];
        } else {
            int* sp = (int*)&sv; int* dp = (int*)&dv;
#pragma unroll
            for (int j = 0; j < 4; ++j) {
                int ee = e + j;
                if (ee < N_EDGES)      { sp[j] = ei[ee]; dp[j] = ei[N_EDGES + ee]; }
                else if (ee < ET)      { sp[j] = dp[j] = ee - N_EDGES; }
                else                   { sp[j] = dp[j] = -1; }
            }
        }
        const int* sp = (const int*)&sv; const int* dp = (const int*)&dv;
#pragma unroll
        for (int j = 0; j < 4; ++j) {
            int i = k * 4 + j;
            int d = dp[j];
            if (d >= 0) {
                int b = d >> BSHIFT;
                bk[i] = (short)b;
                rk[i] = (unsigned short)atomicAdd(&lc[b], 1);
                u[i] = (unsigned)sp[j] | ((unsigned)d << 16);
            } else bk[i] = -1;
        }
    }
    __syncthreads();
    // exclusive scan of 391 counters: first 256, then remaining 135
    int v0 = lc[t];
    int incl0 = block_incl_scan(v0, t, wsum);
    if (t == 255) tot1 = incl0;
    lbl[t] = incl0 - v0;
    __syncthreads();                           // protect wsum + tot1
    int v1 = (t < NBUCK - 256) ? lc[256 + t] : 0;
    int incl1 = block_incl_scan(v1, t, wsum);
    if (t < NBUCK - 256) lbl[256 + t] = tot1 + incl1 - v1;
    __syncthreads();
    // reserve global ranges, record address shift
    for (int b = t; b < NBUCK; b += 256) {
        int c = lc[b];
        if (c) shift[b] = b * CAP + atomicAdd(&bcur[b], c) - lbl[b];
    }
    // scatter into bucket-ordered LDS image
#pragma unroll
    for (int i = 0; i < 16; ++i)
        if (bk[i] >= 0) lrec[lbl[bk[i]] + rk[i]] = u[i];
    __syncthreads();
    int total = lbl[NBUCK - 1] + lc[NBUCK - 1];
    // coalesced write-out: adjacent i -> adjacent global addresses within runs
    for (int i = t; i < total; i += 256) {
        unsigned uu = lrec[i];
        rec[shift[uu >> 23] + i] = uu;         // uu>>23 == dst>>BSHIFT == bucket
    }
}

// ---------------- per-bucket CSR build + edge-weight precompute ----------------
__device__ __forceinline__ int block_incl_scan8(int v, int t, int* wsum) {
    int lane = t & 63, wave = t >> 6;
#pragma unroll
    for (int off = 1; off < 64; off <<= 1) {
        int n = __shfl_up(v, off);
        if (lane >= off) v += n;
    }
    if (lane == 63) wsum[wave] = v;
    __syncthreads();
    int add = 0;
    for (int w = 0; w < wave; ++w) add += wsum[w];
    return v + add;
}

__global__ __launch_bounds__(512) void csrb_kernel(const unsigned* __restrict__ rec,
                                                   const int* __restrict__ bcur,
                                                   const float* __restrict__ as,
                                                   const float* __restrict__ ad,
                                                   int* __restrict__ offsets,
                                                   int* __restrict__ counts,
                                                   unsigned* __restrict__ wcsr) {
    __shared__ unsigned lrec[CAP];            // 18.9 KB
    __shared__ int lcnt[BNODES], loff[BNODES], lcur[BNODES];
    __shared__ float adl[BNODES];
    __shared__ int wsum[8];
    int t = threadIdx.x;
    int b = blockIdx.x;
    int n0 = b << BSHIFT;
    int r0 = b * CAP;
    int cnt_b = bcur[b];
    if (t < BNODES) {
        lcnt[t] = 0; lcur[t] = 0;
        adl[t] = (n0 + t < N_NODES) ? ad[n0 + t] : 0.f;
    }
    for (int i = t; i < cnt_b; i += 512) lrec[i] = rec[r0 + i];
    __syncthreads();
    for (int i = t; i < cnt_b; i += 512)
        atomicAdd(&lcnt[(lrec[i] >> 16) & (BNODES - 1)], 1);
    __syncthreads();
    int v = (t < BNODES) ? lcnt[t] : 0;
    int incl = block_incl_scan8(v, t, wsum);
    if (t < BNODES) {
        loff[t] = incl - v;
        if (n0 + t < N_NODES) { counts[n0 + t] = v; offsets[n0 + t] = r0 + incl - v; }
    }
    __syncthreads();
    for (int i = t; i < cnt_b; i += 512) {
        unsigned u = lrec[i];
        int dl = (u >> 16) & (BNODES - 1);
        int s = u & 0xFFFFu;
        float ev = as[s] + adl[dl];
        ev = ev > 0.f ? ev : SLOPE * ev;
        float w = __expf(ev);
        int pos = atomicAdd(&lcur[dl], 1);
        wcsr[r0 + loff[dl] + pos] =
            (unsigned)s | ((unsigned)__half_as_ushort(__float2half(w)) << 16);
    }
}

// ---------------- gather: wave/dst, 4 edge-streams, depth-8 software pipeline ----------------
#define CONSUME(u_, h_)                                                        \
    {                                                                          \
        float w = __half2float(__ushort_as_half((unsigned short)((u_) >> 16)));\
        float2 f0 = __half22float2(__builtin_bit_cast(__half2, (h_).x));       \
        float2 f1 = __half22float2(__builtin_bit_cast(__half2, (h_).y));       \
        acc.x = fmaf(w, f0.x, acc.x);                                          \
        acc.y = fmaf(w, f0.y, acc.y);                                          \
        acc.z = fmaf(w, f1.x, acc.z);                                          \
        acc.w = fmaf(w, f1.y, acc.w);                                          \
        ws += w;                                                               \
    }
#define STEP(K, u_, h_)                                                        \
    CONSUME(u_, h_);                                                           \
    if (i + 8 + (K) < M8) { u_ = stage[wave][q + (i + 8 + (K)) * 4];           \
                            h_ = xp2[((u_) & 0xFFFFu) * 16 + f]; }

__global__ __launch_bounds__(256) void gather_kernel(const unsigned* __restrict__ wcsr,
                                                     const int* __restrict__ offsets,
                                                     const int* __restrict__ counts,
                                                     const __half* __restrict__ xp,
                                                     const float* __restrict__ bias,
                                                     float* __restrict__ out) {
    __shared__ unsigned stage[4][64];
    int wave = threadIdx.x >> 6, lane = threadIdx.x & 63;
    int d = blockIdx.x * 4 + wave;
    if (d >= N_NODES) return;
    int start = offsets[d], cnt = counts[d];
    int q = lane >> 4, f = lane & 15;
    const uint2* xp2 = (const uint2*)xp;
    float4 acc = make_float4(0.f, 0.f, 0.f, 0.f);
    float ws = 0.f;

    for (int jb = 0; jb < cnt; jb += 64) {
        int iters = min(cnt - jb, 64);
        unsigned rc = (lane < iters) ? wcsr[start + jb + lane] : 0u;
        stage[wave][lane] = rc;               // wave-private; lanes >= iters write 0
        int m = (iters - q + 3) >> 2;         // this quarter's edge count
        int M8 = (m + 7) & ~7;                // rounded up to 8; extras have u=0 -> w=0
        unsigned u0 = stage[wave][q];
        unsigned u1 = stage[wave][q + 4];
        unsigned u2 = stage[wave][q + 8];
        unsigned u3 = stage[wave][q + 12];
        unsigned u4 = stage[wave][q + 16];
        unsigned u5 = stage[wave][q + 20];
        unsigned u6 = stage[wave][q + 24];
        unsigned u7 = stage[wave][q + 28];
        uint2 h0 = xp2[(u0 & 0xFFFFu) * 16 + f];
        uint2 h1 = xp2[(u1 & 0xFFFFu) * 16 + f];
        uint2 h2 = xp2[(u2 & 0xFFFFu) * 16 + f];
        uint2 h3 = xp2[(u3 & 0xFFFFu) * 16 + f];
        uint2 h4 = xp2[(u4 & 0xFFFFu) * 16 + f];
        uint2 h5 = xp2[(u5 & 0xFFFFu) * 16 + f];
        uint2 h6 = xp2[(u6 & 0xFFFFu) * 16 + f];
        uint2 h7 = xp2[(u7 & 0xFFFFu) * 16 + f];
        for (int i = 0; i < M8; i += 8) {
            STEP(0, u0, h0);
            STEP(1, u1, h1);
            STEP(2, u2, h2);
            STEP(3, u3, h3);
            STEP(4, u4, h4);
            STEP(5, u5, h5);
            STEP(6, u6, h6);
            STEP(7, u7, h7);
        }
    }
#pragma unroll
    for (int off = 16; off < 64; off <<= 1) {
        acc.x += __shfl_xor(acc.x, off);
        acc.y += __shfl_xor(acc.y, off);
        acc.z += __shfl_xor(acc.z, off);
        acc.w += __shfl_xor(acc.w, off);
        ws    += __shfl_xor(ws, off);
    }
    if (q == 0) {
        float inv = 1.f / ws;
        float4 bl = ((const float4*)bias)[f];
        float4 o;
        o.x = fmaf(acc.x, inv, bl.x);
        o.y = fmaf(acc.y, inv, bl.y);
        o.z = fmaf(acc.z, inv, bl.z);
        o.w = fmaf(acc.w, inv, bl.w);
        o.x = o.x > 0.f ? o.x : 0.f;
        o.y = o.y > 0.f ? o.y : 0.f;
        o.z = o.z > 0.f ? o.z : 0.f;
        o.w = o.w > 0.f ? o.w : 0.f;
        ((float4*)out)[(size_t)d * 16 + f] = o;
    }
}

extern "C" void kernel_launch(void* const* d_in, const int* in_sizes, int n_in,
                              void* d_out, int out_size, void* d_ws, size_t ws_size,
                              hipStream_t stream) {
    const float* x     = (const float*)d_in[0];
    const float* W     = (const float*)d_in[1];
    const float* a_src = (const float*)d_in[2];
    const float* a_dst = (const float*)d_in[3];
    const float* bias  = (const float*)d_in[4];
    const int*   ei    = (const int*)d_in[5];
    float* out = (float*)d_out;

    _Float16* xph   = (_Float16*)d_ws;                        // N*64 fp16
    float*  as      = (float*)(xph + (size_t)N_NODES * F_OUT);
    float*  ad      = as + N_NODES;
    int*    counts  = (int*)(ad + N_NODES);                   // N
    int*    offsets = counts + N_NODES;                       // N
    int*    bcur    = offsets + N_NODES;                      // NBUCK
    unsigned* rec   = (unsigned*)(bcur + NBUCK + 64);         // NBUCK*CAP u32
    unsigned* wcsr  = rec + (size_t)NBUCK * CAP;              // NBUCK*CAP u32

    gemm_kernel<<<(N_NODES + 63) / 64, 256, 0, stream>>>(
        (const float4*)x, W, a_src, a_dst, xph, as, ad, bcur);
    part_kernel<<<PBLOCKS, 256, 0, stream>>>(ei, bcur, rec);
    csrb_kernel<<<NBUCK, 512, 0, stream>>>(rec, bcur, as, ad, offsets, counts, wcsr);
    gather_kernel<<<(N_NODES + 3) / 4, 256, 0, stream>>>(wcsr, offsets, counts,
                                                         (const __half*)xph, bias, out);
}

// Round 13
// 83.593 us; speedup vs baseline: 1.1429x; 1.0425x over previous
//
#include <hip/hip_runtime.h>
#include <hip/hip_fp16.h>
#include <math.h>

#define N_NODES 50000
#define N_EDGES 1600000
#define ET (N_EDGES + N_NODES)
#define F_OUT 64
#define F_IN 128
#define SLOPE 0.2f
#define BSHIFT 7                               // 128 nodes per bucket
#define BNODES 128
#define NBUCK ((N_NODES + BNODES - 1) >> BSHIFT)   // 391 buckets
#define CAP 4736                               // mean 4224 + 8 sigma
#define EPB 4096                               // edges per partition block
#define PBLOCKS ((ET + EPB - 1) / EPB)         // 403

typedef _Float16 half8 __attribute__((ext_vector_type(8)));
typedef _Float16 half4 __attribute__((ext_vector_type(4)));
typedef float f32x4 __attribute__((ext_vector_type(4)));

// ---------------- MFMA GEMM: xp(f16) = x @ W + attention logits (+bcur zero) ----------------
__global__ __launch_bounds__(256) void gemm_kernel(const float4* __restrict__ x4,
                                                   const float* __restrict__ W,
                                                   const float* __restrict__ a_src,
                                                   const float* __restrict__ a_dst,
                                                   _Float16* __restrict__ xph,
                                                   float* __restrict__ alpha_s,
                                                   float* __restrict__ alpha_d,
                                                   int* __restrict__ bcur) {
    __shared__ _Float16 xs[64][136];          // padded: row stride 272B
    int t = threadIdx.x;
    if (blockIdx.x == 0)
        for (int i = t; i < NBUCK; i += 256) bcur[i] = 0;
    int wave = t >> 6, lane = t & 63;
    int g = lane >> 4, c16 = lane & 15;

    size_t rbase = (size_t)blockIdx.x * 64;
#pragma unroll
    for (int i = 0; i < 8; ++i) {
        int idx = t + i * 256;                 // over 64*32 float4
        int row = idx >> 5, c4 = idx & 31;
        size_t gr = rbase + row;
        if (gr >= N_NODES) gr = N_NODES - 1;
        float4 v = x4[gr * (F_IN / 4) + c4];
        half4 hv = { (_Float16)v.x, (_Float16)v.y, (_Float16)v.z, (_Float16)v.w };
        *(half4*)&xs[row][c4 * 4] = hv;
    }

    // B fragments straight from global W (L2-resident 32 KB)
    half8 bw[4][4];
#pragma unroll
    for (int nt = 0; nt < 4; ++nt)
#pragma unroll
        for (int kt = 0; kt < 4; ++kt) {
            int col = nt * 16 + c16;
            int k0 = kt * 32 + g * 8;
#pragma unroll
            for (int e = 0; e < 8; ++e)
                bw[nt][kt][e] = (_Float16)W[(k0 + e) * F_OUT + col];
        }
    __syncthreads();

    int r0 = wave * 16;
    half8 af[4];
#pragma unroll
    for (int kt = 0; kt < 4; ++kt)
        af[kt] = *(const half8*)&xs[r0 + c16][kt * 32 + g * 8];

    f32x4 acc[4];
#pragma unroll
    for (int nt = 0; nt < 4; ++nt) {
        acc[nt] = (f32x4){0.f, 0.f, 0.f, 0.f};
#pragma unroll
        for (int kt = 0; kt < 4; ++kt)
            acc[nt] = __builtin_amdgcn_mfma_f32_16x16x32_f16(af[kt], bw[nt][kt], acc[nt], 0, 0, 0);
    }

    int growbase = (int)rbase + r0 + g * 4;
#pragma unroll
    for (int nt = 0; nt < 4; ++nt) {
#pragma unroll
        for (int r = 0; r < 4; ++r) {
            int row = growbase + r;
            if (row < N_NODES)
                xph[(size_t)row * F_OUT + nt * 16 + c16] = (_Float16)acc[nt][r];
        }
    }
    float asl[4], adl[4];
#pragma unroll
    for (int nt = 0; nt < 4; ++nt) {
        asl[nt] = a_src[nt * 16 + c16];
        adl[nt] = a_dst[nt * 16 + c16];
    }
#pragma unroll
    for (int r = 0; r < 4; ++r) {
        float ps = 0.f, pd = 0.f;
#pragma unroll
        for (int nt = 0; nt < 4; ++nt) {
            ps = fmaf(acc[nt][r], asl[nt], ps);
            pd = fmaf(acc[nt][r], adl[nt], pd);
        }
#pragma unroll
        for (int off = 1; off < 16; off <<= 1) {
            ps += __shfl_xor(ps, off);
            pd += __shfl_xor(pd, off);
        }
        int row = growbase + r;
        if (c16 == 0 && row < N_NODES) { alpha_s[row] = ps; alpha_d[row] = pd; }
    }
}

// ---------------- partition: single-pass rank capture, 16 edges/thread ----------------
__global__ __launch_bounds__(256) void part_kernel(const int* __restrict__ ei,
                                                   int* __restrict__ bcur,
                                                   unsigned* __restrict__ rec) {
    __shared__ int lc[NBUCK];
    __shared__ int lbase[NBUCK];
    int t = threadIdx.x;
    for (int b = t; b < NBUCK; b += 256) lc[b] = 0;
    __syncthreads();
    int e0 = blockIdx.x * EPB;

    unsigned u[16]; short bk[16]; unsigned short rk[16];
#pragma unroll
    for (int k = 0; k < 4; ++k) {
        int e = e0 + k * 1024 + t * 4;
        int4 sv, dv;
        if (e + 3 < N_EDGES) {                 // fast path: 16B aligned vector loads
            sv = *(const int4*)&ei[e];
            dv = *(const int4*)&ei[N_EDGES + e];
        } else {
            int* sp = (int*)&sv; int* dp = (int*)&dv;
#pragma unroll
            for (int j = 0; j < 4; ++j) {
                int ee = e + j;
                if (ee < N_EDGES)      { sp[j] = ei[ee]; dp[j] = ei[N_EDGES + ee]; }
                else if (ee < ET)      { sp[j] = dp[j] = ee - N_EDGES; }
                else                   { sp[j] = dp[j] = -1; }
            }
        }
        const int* sp = (const int*)&sv; const int* dp = (const int*)&dv;
#pragma unroll
        for (int j = 0; j < 4; ++j) {
            int i = k * 4 + j;
            int d = dp[j];
            if (d >= 0) {
                int b = d >> BSHIFT;
                bk[i] = (short)b;
                rk[i] = (unsigned short)atomicAdd(&lc[b], 1);
                u[i] = (unsigned)sp[j] | ((unsigned)d << 16);
            } else bk[i] = -1;
        }
    }
    __syncthreads();
    for (int b = t; b < NBUCK; b += 256)
        lbase[b] = lc[b] ? (b * CAP + atomicAdd(&bcur[b], lc[b])) : 0;
    __syncthreads();
#pragma unroll
    for (int i = 0; i < 16; ++i)
        if (bk[i] >= 0) rec[lbase[bk[i]] + rk[i]] = u[i];
}

// ---------------- scan helper (8 waves) ----------------
__device__ __forceinline__ int block_incl_scan(int v, int t, int* wsum) {
    int lane = t & 63, wave = t >> 6;
#pragma unroll
    for (int off = 1; off < 64; off <<= 1) {
        int n = __shfl_up(v, off);
        if (lane >= off) v += n;
    }
    if (lane == 63) wsum[wave] = v;
    __syncthreads();
    int add = 0;
    for (int w = 0; w < wave; ++w) add += wsum[w];
    return v + add;
}

// ---------------- per-bucket CSR build + edge-weight precompute ----------------
__global__ __launch_bounds__(512) void csrb_kernel(const unsigned* __restrict__ rec,
                                                   const int* __restrict__ bcur,
                                                   const float* __restrict__ as,
                                                   const float* __restrict__ ad,
                                                   int* __restrict__ offsets,
                                                   int* __restrict__ counts,
                                                   unsigned* __restrict__ wcsr) {
    __shared__ unsigned lrec[CAP];            // 18.9 KB
    __shared__ int lcnt[BNODES], loff[BNODES], lcur[BNODES];
    __shared__ float adl[BNODES];
    __shared__ int wsum[8];
    int t = threadIdx.x;
    int b = blockIdx.x;
    int n0 = b << BSHIFT;
    int r0 = b * CAP;
    int cnt_b = bcur[b];
    if (t < BNODES) {
        lcnt[t] = 0; lcur[t] = 0;
        adl[t] = (n0 + t < N_NODES) ? ad[n0 + t] : 0.f;
    }
    for (int i = t; i < cnt_b; i += 512) lrec[i] = rec[r0 + i];
    __syncthreads();
    for (int i = t; i < cnt_b; i += 512)
        atomicAdd(&lcnt[(lrec[i] >> 16) & (BNODES - 1)], 1);
    __syncthreads();
    int v = (t < BNODES) ? lcnt[t] : 0;
    int incl = block_incl_scan(v, t, wsum);
    if (t < BNODES) {
        loff[t] = incl - v;
        if (n0 + t < N_NODES) { counts[n0 + t] = v; offsets[n0 + t] = r0 + incl - v; }
    }
    __syncthreads();
    for (int i = t; i < cnt_b; i += 512) {
        unsigned u = lrec[i];
        int dl = (u >> 16) & (BNODES - 1);
        int s = u & 0xFFFFu;
        float ev = as[s] + adl[dl];
        ev = ev > 0.f ? ev : SLOPE * ev;
        float w = __expf(ev);
        int pos = atomicAdd(&lcur[dl], 1);
        wcsr[r0 + loff[dl] + pos] =
            (unsigned)s | ((unsigned)__half_as_ushort(__float2half(w)) << 16);
    }
}

// ---------------- gather: wave/dst, 8 edge-streams x 8 lanes, uint4 row loads ----------------
#define CONS(u_, h_)                                                           \
    {                                                                          \
        float w = __half2float(__ushort_as_half((unsigned short)((u_) >> 16)));\
        float2 p;                                                              \
        p = __half22float2(__builtin_bit_cast(__half2, (h_).x));               \
        a0 = fmaf(w, p.x, a0); a1 = fmaf(w, p.y, a1);                          \
        p = __half22float2(__builtin_bit_cast(__half2, (h_).y));               \
        a2 = fmaf(w, p.x, a2); a3 = fmaf(w, p.y, a3);                          \
        p = __half22float2(__builtin_bit_cast(__half2, (h_).z));               \
        a4 = fmaf(w, p.x, a4); a5 = fmaf(w, p.y, a5);                          \
        p = __half22float2(__builtin_bit_cast(__half2, (h_).w));               \
        a6 = fmaf(w, p.x, a6); a7 = fmaf(w, p.y, a7);                          \
        ws += w;                                                               \
    }

__global__ __launch_bounds__(256) void gather_kernel(const unsigned* __restrict__ wcsr,
                                                     const int* __restrict__ offsets,
                                                     const int* __restrict__ counts,
                                                     const __half* __restrict__ xp,
                                                     const float* __restrict__ bias,
                                                     float* __restrict__ out) {
    __shared__ unsigned stage[4][64];
    int wave = threadIdx.x >> 6, lane = threadIdx.x & 63;
    int d = blockIdx.x * 4 + wave;
    if (d >= N_NODES) return;
    int start = offsets[d], cnt = counts[d];
    int o = lane >> 3, f8 = lane & 7;          // stream o, feature-oct f8
    const uint4* xp4 = (const uint4*)xp;       // 16 B = 8 halves
    float a0 = 0.f, a1 = 0.f, a2 = 0.f, a3 = 0.f;
    float a4 = 0.f, a5 = 0.f, a6 = 0.f, a7 = 0.f;
    float ws = 0.f;

    for (int jb = 0; jb < cnt; jb += 64) {
        int iters = min(cnt - jb, 64);
        stage[wave][lane] = (lane < iters) ? wcsr[start + jb + lane] : 0u;
        // wave-private row: in-order within wave, no barrier needed
        unsigned u0 = stage[wave][o];
        unsigned u1 = stage[wave][o + 8];
        unsigned u2 = stage[wave][o + 16];
        unsigned u3 = stage[wave][o + 24];
        unsigned u4 = stage[wave][o + 32];
        unsigned u5 = stage[wave][o + 40];
        unsigned u6 = stage[wave][o + 48];
        unsigned u7 = stage[wave][o + 56];
        uint4 h0 = xp4[(u0 & 0xFFFFu) * 8 + f8];
        uint4 h1 = xp4[(u1 & 0xFFFFu) * 8 + f8];
        uint4 h2 = xp4[(u2 & 0xFFFFu) * 8 + f8];
        uint4 h3 = xp4[(u3 & 0xFFFFu) * 8 + f8];
        uint4 h4 = xp4[(u4 & 0xFFFFu) * 8 + f8];
        uint4 h5 = xp4[(u5 & 0xFFFFu) * 8 + f8];
        uint4 h6 = xp4[(u6 & 0xFFFFu) * 8 + f8];
        uint4 h7 = xp4[(u7 & 0xFFFFu) * 8 + f8];
        // padded entries are u=0 -> w=0 (harmless hot-line loads of row 0)
        CONS(u0, h0);
        CONS(u1, h1);
        CONS(u2, h2);
        CONS(u3, h3);
        CONS(u4, h4);
        CONS(u5, h5);
        CONS(u6, h6);
        CONS(u7, h7);
    }
    // reduce across the 8 streams (lanes differing in bits 3..5)
#pragma unroll
    for (int off = 8; off < 64; off <<= 1) {
        a0 += __shfl_xor(a0, off);
        a1 += __shfl_xor(a1, off);
        a2 += __shfl_xor(a2, off);
        a3 += __shfl_xor(a3, off);
        a4 += __shfl_xor(a4, off);
        a5 += __shfl_xor(a5, off);
        a6 += __shfl_xor(a6, off);
        a7 += __shfl_xor(a7, off);
        ws += __shfl_xor(ws, off);
    }
    if (o == 0) {
        float inv = 1.f / ws;
        float4 b0 = ((const float4*)bias)[f8 * 2];
        float4 b1 = ((const float4*)bias)[f8 * 2 + 1];
        float4 o0, o1;
        o0.x = fmaf(a0, inv, b0.x); o0.y = fmaf(a1, inv, b0.y);
        o0.z = fmaf(a2, inv, b0.z); o0.w = fmaf(a3, inv, b0.w);
        o1.x = fmaf(a4, inv, b1.x); o1.y = fmaf(a5, inv, b1.y);
        o1.z = fmaf(a6, inv, b1.z); o1.w = fmaf(a7, inv, b1.w);
        o0.x = o0.x > 0.f ? o0.x : 0.f;
        o0.y = o0.y > 0.f ? o0.y : 0.f;
        o0.z = o0.z > 0.f ? o0.z : 0.f;
        o0.w = o0.w > 0.f ? o0.w : 0.f;
        o1.x = o1.x > 0.f ? o1.x : 0.f;
        o1.y = o1.y > 0.f ? o1.y : 0.f;
        o1.z = o1.z > 0.f ? o1.z : 0.f;
        o1.w = o1.w > 0.f ? o1.w : 0.f;
        ((float4*)out)[(size_t)d * 16 + f8 * 2]     = o0;
        ((float4*)out)[(size_t)d * 16 + f8 * 2 + 1] = o1;
    }
}

extern "C" void kernel_launch(void* const* d_in, const int* in_sizes, int n_in,
                              void* d_out, int out_size, void* d_ws, size_t ws_size,
                              hipStream_t stream) {
    const float* x     = (const float*)d_in[0];
    const float* W     = (const float*)d_in[1];
    const float* a_src = (const float*)d_in[2];
    const float* a_dst = (const float*)d_in[3];
    const float* bias  = (const float*)d_in[4];
    const int*   ei    = (const int*)d_in[5];
    float* out = (float*)d_out;

    _Float16* xph   = (_Float16*)d_ws;                        // N*64 fp16
    float*  as      = (float*)(xph + (size_t)N_NODES * F_OUT);
    float*  ad      = as + N_NODES;
    int*    counts  = (int*)(ad + N_NODES);                   // N
    int*    offsets = counts + N_NODES;                       // N
    int*    bcur    = offsets + N_NODES;                      // NBUCK
    unsigned* rec   = (unsigned*)(bcur + NBUCK + 64);         // NBUCK*CAP u32
    unsigned* wcsr  = rec + (size_t)NBUCK * CAP;              // NBUCK*CAP u32

    gemm_kernel<<<(N_NODES + 63) / 64, 256, 0, stream>>>(
        (const float4*)x, W, a_src, a_dst, xph, as, ad, bcur);
    part_kernel<<<PBLOCKS, 256, 0, stream>>>(ei, bcur, rec);
    csrb_kernel<<<NBUCK, 512, 0, stream>>>(rec, bcur, as, ad, offsets, counts, wcsr);
    gather_kernel<<<(N_NODES + 3) / 4, 256, 0, stream>>>(wcsr, offsets, counts,
                                                         (const __half*)xph, bias, out);
}